// Round 7
// baseline (162.203 us; speedup 1.0000x reference)
//
#include <hip/hip_runtime.h>
#include <stdint.h>

#define HIDDEN 768
#define EMBED  512
#define BATCH  16
#define SEQ    512
#define NWORDS (BATCH*SEQ)      // 8192
#define NKC    (HIDDEN/8)       // 96 chunks of 8 bf16
#define PAD_FLAT_IDX 2047       // flat index of words[0, 511, 3]
#define NEG_SLOPE 0.1f

__device__ __forceinline__ unsigned short f2bf(float f) {
    unsigned int x = __float_as_uint(f);
    unsigned int r = x + 0x7fffu + ((x >> 16) & 1u);
    return (unsigned short)(r >> 16);
}

// ---------------------------------------------------------------------------
// Kernel 1 (prep, R4-verbatim — correctness-verified): blocks 0..15 ->
// per-batch stable-compaction scan writing inverse gather descriptors per
// OUTPUT row (ids compacted to front; pad row -> {pid},cnt=1).
// blocks 16..399 -> w_ffn [768,512] f32 -> wtk bf16 K-major:
//   wtk[kc][n][ko] = w[kc*8+ko][n],  kc 0..95, n 0..511, ko 0..7.
// ---------------------------------------------------------------------------
__global__ __launch_bounds__(256) void prep_kernel(const int* __restrict__ words,
                                                   const float* __restrict__ w,
                                                   int4* __restrict__ ids4,
                                                   int* __restrict__ cnts,
                                                   unsigned short* __restrict__ wtk) {
    if (blockIdx.x < BATCH) {
        int b = blockIdx.x;
        int t = threadIdx.x;          // 0..255; handles words 2t, 2t+1
        int s0 = 2 * t, s1 = 2 * t + 1;
        int4 wa = ((const int4*)words)[b * SEQ + s0];
        int4 wb = ((const int4*)words)[b * SEQ + s1];
        bool v0 = (wa.x | wa.y | wa.z | wa.w) != 0;
        bool v1 = (wb.x | wb.y | wb.z | wb.w) != 0;

        unsigned long long m0 = __ballot(v0);
        unsigned long long m1 = __ballot(v1);
        int lane = t & 63;
        int wave = t >> 6;            // 0..3
        unsigned long long below = (1ull << lane) - 1ull;
        int pre = __popcll(m0 & below) + __popcll(m1 & below);
        __shared__ int wsum[4];
        if (lane == 0) wsum[wave] = __popcll(m0) + __popcll(m1);
        __syncthreads();
        int off = 0, tot = 0;
#pragma unroll
        for (int i = 0; i < 4; ++i) {
            int x = wsum[i];
            if (i < wave) off += x;
            tot += x;
        }
        int vp0 = off + pre;
        int vp1 = vp0 + (v0 ? 1 : 0);
        int d0 = v0 ? vp0 : (tot + (s0 - vp0));   // bijective over [0,SEQ)
        int d1 = v1 ? vp1 : (tot + (s1 - vp1));

        int pid = words[PAD_FLAT_IDX];
        {
            int id[4] = {wa.x, wa.y, wa.z, wa.w};
            int o[4] = {0, 0, 0, 0};
            int c = 0;
#pragma unroll
            for (int j = 0; j < 4; ++j) if (id[j] != 0) o[c++] = id[j];
            if (c == 0) { o[0] = pid; c = 1; }
            ids4[b * SEQ + d0] = make_int4(o[0], o[1], o[2], o[3]);
            cnts[b * SEQ + d0] = c;
        }
        {
            int id[4] = {wb.x, wb.y, wb.z, wb.w};
            int o[4] = {0, 0, 0, 0};
            int c = 0;
#pragma unroll
            for (int j = 0; j < 4; ++j) if (id[j] != 0) o[c++] = id[j];
            if (c == 0) { o[0] = pid; c = 1; }
            ids4[b * SEQ + d1] = make_int4(o[0], o[1], o[2], o[3]);
            cnts[b * SEQ + d1] = c;
        }
    } else {
        __shared__ float tile[32][33];
        int bid = blockIdx.x - BATCH;       // 0..383
        int k0 = (bid % (HIDDEN / 32)) * 32;
        int n0 = (bid / (HIDDEN / 32)) * 32;
        int tc = threadIdx.x & 31;
        int tr = threadIdx.x >> 5;          // 0..7
#pragma unroll
        for (int i = 0; i < 4; ++i) {
            int r = tr + i * 8;
            tile[r][tc] = w[(size_t)(k0 + r) * EMBED + n0 + tc];
        }
        __syncthreads();
        int kc = (k0 >> 3) + (tc >> 3);
        int ko = tc & 7;
#pragma unroll
        for (int i = 0; i < 4; ++i) {
            int n = n0 + tr + i * 8;
            wtk[(size_t)kc * (EMBED * 8) + n * 8 + ko] = f2bf(tile[tc][n - n0]);
        }
    }
}

// ---------------------------------------------------------------------------
// Kernel 2 (fused gather+pool+GEMM+bias+LeakyReLU).
// 256 blocks x 512 threads (8 waves) = 8 waves/CU. Block = 32 output rows x
// full N=512. Per K-iter (BK=32):
//   - B-slice [4][512][8] staged via global_load_lds w16 (linear: q=j, n=tid;
//     frag reads hit banks n*4%32 -> 2-way, free).
//   - threads 0..255 gather: 8 lanes/row, lane loads float4 of each of 4
//     subword-row k-slices (128 B coalesced/row/subword), weighted fp32 sum
//     (w_j=0 for padded slots -> branch-free), bf16 -> ds_write 8 B into
//     A-slice [q][32][8] (2 KB).
//   - 8 MFMA 16x16x32 per wave (wave tile 32x64).
// Gather overlaps MFMA across waves; no xseq round-trip; no scan kernel.
// ---------------------------------------------------------------------------
typedef __attribute__((ext_vector_type(8))) short bf16x8;
typedef __attribute__((ext_vector_type(4))) float f32x4;

__device__ __forceinline__ void load_lds16(const void* g, void* l) {
    __builtin_amdgcn_global_load_lds(
        (const __attribute__((address_space(1))) unsigned int*)g,
        (__attribute__((address_space(3))) unsigned int*)l,
        16, 0, 0);
}

__global__ __launch_bounds__(512) void fused_kernel(const int4* __restrict__ ids4,
                                                    const int* __restrict__ cnts,
                                                    const float* __restrict__ table,
                                                    const unsigned short* __restrict__ wtk,
                                                    const float* __restrict__ bias,
                                                    float* __restrict__ out) {
    __shared__ unsigned short sB[4 * EMBED * 8];   // 32 KB  [q][n][8]
    __shared__ unsigned short sA[4 * 32 * 8];      //  2 KB  [q][row][8]

    int tid  = threadIdx.x;
    int wave = tid >> 6;         // 0..7 -> 64-col slab
    int lane = tid & 63;
    int quad = lane >> 4;
    int l16  = lane & 15;
    int m0   = blockIdx.x * 32;

    // ---- gather setup (threads 0..255: group = row, 8 lanes each) ----
    int grow = tid >> 3;         // 0..31 (only meaningful for tid<256)
    int gl   = tid & 7;          // 0..7
    const float* gp[4];
    float gw[4];
    {
        int r = (tid < 256) ? (m0 + grow) : m0;   // clamp for inactive threads
        int4 w4 = ids4[r];
        int cnt = cnts[r];
        float inv = 1.0f / (float)cnt;
        int idj[4] = {w4.x, w4.y, w4.z, w4.w};
#pragma unroll
        for (int j = 0; j < 4; ++j) {
            gw[j] = (j < cnt) ? inv : 0.0f;       // padded slots: weight 0
            gp[j] = table + (size_t)idj[j] * HIDDEN + gl * 4;
        }
    }

    f32x4 acc[2][4] = {};

    for (int k0 = 0; k0 < HIDDEN; k0 += 32) {
        int kc0 = k0 >> 3;
        // ---- stage B-slice: chunk (q=j, n=tid), perfectly linear ----
#pragma unroll
        for (int j = 0; j < 4; ++j)
            load_lds16(wtk + (size_t)(kc0 + j) * (EMBED * 8) + tid * 8,
                       &sB[(j * EMBED + tid) * 8]);

        // ---- gather + pool this k-slice ----
        if (tid < 256) {
            float4 a = *(const float4*)(gp[0] + k0);
            float4 b = *(const float4*)(gp[1] + k0);
            float4 c = *(const float4*)(gp[2] + k0);
            float4 d = *(const float4*)(gp[3] + k0);
            float4 s;
            s.x = gw[0] * a.x + gw[1] * b.x + gw[2] * c.x + gw[3] * d.x;
            s.y = gw[0] * a.y + gw[1] * b.y + gw[2] * c.y + gw[3] * d.y;
            s.z = gw[0] * a.z + gw[1] * b.z + gw[2] * c.z + gw[3] * d.z;
            s.w = gw[0] * a.w + gw[1] * b.w + gw[2] * c.w + gw[3] * d.w;
            ushort4 o;
            o.x = f2bf(s.x); o.y = f2bf(s.y); o.z = f2bf(s.z); o.w = f2bf(s.w);
            // lane covers k = gl*4..gl*4+3 -> q = gl>>1, half = gl&1
            *(ushort4*)&sA[((gl >> 1) * 32 + grow) * 8 + (gl & 1) * 4] = o;
        }
        __syncthreads();

        bf16x8 af[2], bfr[4];
#pragma unroll
        for (int mt = 0; mt < 2; ++mt)
            af[mt] = *(const bf16x8*)&sA[(quad * 32 + mt * 16 + l16) * 8];
#pragma unroll
        for (int nt = 0; nt < 4; ++nt)
            bfr[nt] = *(const bf16x8*)&sB[(quad * EMBED + wave * 64 + nt * 16 + l16) * 8];

#pragma unroll
        for (int mt = 0; mt < 2; ++mt)
#pragma unroll
            for (int nt = 0; nt < 4; ++nt)
                acc[mt][nt] = __builtin_amdgcn_mfma_f32_16x16x32_bf16(
                    af[mt], bfr[nt], acc[mt][nt], 0, 0, 0);
        __syncthreads();
    }

    // ---- epilogue: bias + LeakyReLU + store (D row = quad*4+r, col = l16) ----
#pragma unroll
    for (int nt = 0; nt < 4; ++nt) {
        int col = wave * 64 + nt * 16 + l16;
        float bv = bias[col];
#pragma unroll
        for (int mt = 0; mt < 2; ++mt) {
            int rbase = m0 + mt * 16 + quad * 4;
#pragma unroll
            for (int r = 0; r < 4; ++r) {
                float v = acc[mt][nt][r] + bv;
                v = (v > 0.f) ? v : v * NEG_SLOPE;
                out[(size_t)(rbase + r) * EMBED + col] = v;
            }
        }
    }
}

// ---------------------------------------------------------------------------
extern "C" void kernel_launch(void* const* d_in, const int* in_sizes, int n_in,
                              void* d_out, int out_size, void* d_ws, size_t ws_size,
                              hipStream_t stream) {
    (void)in_sizes; (void)n_in; (void)out_size; (void)ws_size;
    const int*   words = (const int*)d_in[0];
    const float* table = (const float*)d_in[1];
    const float* wffn  = (const float*)d_in[2];
    const float* bffn  = (const float*)d_in[3];
    float* out = (float*)d_out;

    char* ws = (char*)d_ws;
    unsigned short* wtk  = (unsigned short*)ws;                  // 786432 B
    int4*           ids4 = (int4*)(ws + 786432);                 // 131072 B
    int*            cnts = (int*)(ws + 786432 + 131072);         //  32768 B

    prep_kernel<<<BATCH + (HIDDEN / 32) * (EMBED / 32), 256, 0, stream>>>(
        words, wffn, ids4, cnts, wtk);
    fused_kernel<<<NWORDS / 32, 512, 0, stream>>>(ids4, cnts, table, wtk, bffn, out);
}